// Round 15
// baseline (290.102 us; speedup 1.0000x reference)
//
#include <hip/hip_runtime.h>
#include <hip/hip_bf16.h>
#include <climits>

typedef __bf16 bf16;
typedef __bf16 bf16x4 __attribute__((ext_vector_type(4)));
typedef __bf16 bf16x8 __attribute__((ext_vector_type(8)));
typedef float f32x4 __attribute__((ext_vector_type(4)));

#define NB 8
#define L_ 4096
#define C_ 512
#define KW 5
#define NS 8

#define GLOAD_LDS16(g, l)                                                      \
  __builtin_amdgcn_global_load_lds(                                            \
      (const __attribute__((address_space(1))) void*)(g),                      \
      (__attribute__((address_space(3))) void*)(l), 16, 0, 0)

// ---------------------------------------------------------------------------
// prep (merged, unchanged from R14): blocks 0..127 pack w_pw -> bf16 B-frag
// order; blocks 128..639 compute bias2 = b_pw + w_pw . b_dw (fp32-exact).
// ---------------------------------------------------------------------------
__global__ __launch_bounds__(256) void prep_kernel(
    const float* __restrict__ w_pw, const float* __restrict__ b_dw,
    const float* __restrict__ b_pw, bf16* __restrict__ pk,
    float* __restrict__ bias2) {
  const int t = threadIdx.x;
  if (blockIdx.x < 128) {
    const int gid = blockIdx.x * 256 + t;  // 0..32767
    const int lane = gid & 63;
    const int nf = (gid >> 6) & 3;
    const int wnn = (gid >> 8) & 7;
    const int kk = gid >> 11;
    const int n = wnn * 64 + nf * 16 + (lane & 15);
    const int c = kk * 32 + (lane >> 4) * 8;
    const float* s = w_pw + n * C_ + c;
    float4 a = *(const float4*)s;
    float4 b4 = *(const float4*)(s + 4);
    bf16x8 h;
    h[0] = (bf16)a.x; h[1] = (bf16)a.y; h[2] = (bf16)a.z; h[3] = (bf16)a.w;
    h[4] = (bf16)b4.x; h[5] = (bf16)b4.y; h[6] = (bf16)b4.z; h[7] = (bf16)b4.w;
    *(bf16x8*)(pk + (size_t)gid * 8) = h;
  } else {
    const int n = blockIdx.x - 128;  // 0..511
    float2 v = *(const float2*)(w_pw + n * C_ + 2 * t);
    float2 bb = *(const float2*)(b_dw + 2 * t);
    float s = v.x * bb.x + v.y * bb.y;
#pragma unroll
    for (int off = 32; off; off >>= 1) s += __shfl_down(s, off, 64);
    __shared__ float part[4];
    if ((t & 63) == 0) part[t >> 6] = s;
    __syncthreads();
    if (t == 0) bias2[n] = b_pw[n] + part[0] + part[1] + part[2] + part[3];
  }
}

// ---------------------------------------------------------------------------
// pc_kernel: heterogeneous producer/consumer blocks, flag handshake.
//  blocks 0..127   PRODUCERS: register rolling-window segment-causal conv,
//    256 rows/block (512 thr = 128 ch-quads x 4 spans of 64 rows), dw written
//    bf16 to workspace with per-row quad-XOR swizzle (coalesced 512B/wave),
//    then agent-release flags for its 4 tiles.
//  blocks 128..383 CONSUMERS: 2 tiles of 64 rows each. Per tile: spin-acquire
//    flag -> threadfence -> 64KB linear DMA (pre-swizzled source) -> R14's
//    barrier-free packed-B GEMM (8 waves x 64 cols, acc[4][4]) -> epilogue.
//  All 384 blocks co-resident by capacity (64KB LDS -> 2/CU, 512 slots;
//  16 waves/CU) => no dispatch-order assumption, no deadlock.
// ---------------------------------------------------------------------------
__global__ __launch_bounds__(512, 2) void pc_kernel(
    const float* __restrict__ x, const int* __restrict__ segb,
    const float* __restrict__ w_dw, const bf16* __restrict__ pk,
    const float* __restrict__ bias2, bf16* __restrict__ dwg,
    int* __restrict__ flags, float* __restrict__ out) {
  __shared__ __align__(16) bf16 As[64 * C_];  // 64 KB (consumers only)

  const int t = threadIdx.x;
  const int lane = t & 63;
  const f32x4 z4 = (f32x4){0.f, 0.f, 0.f, 0.f};

  if (blockIdx.x < 128) {
    // ========================= PRODUCER =========================
    const int blk = blockIdx.x;
    const int b = blk >> 4;               // 16 blocks per batch row
    const int rbase = (blk & 15) << 8;    // 256 rows
    const int q = t & 127;                // channel quad
    const int span = t >> 7;              // 0..3
    const int lrow0 = rbase + span * 64;  // 64 rows per thread

    float4 raw[5];
#pragma unroll
    for (int i = 0; i < 5; ++i)
      raw[i] = *(const float4*)(w_dw + q * 20 + i * 4);
    f32x4 wt[5];
#pragma unroll
    for (int m = 0; m < 5; ++m)
#pragma unroll
      for (int i = 0; i < 4; ++i) {
        const int f = i * 5 + m;
        wt[m][i] = ((const float*)&raw[f >> 2])[f & 3];
      }

    const int* sb = segb + b * NS * 2;
    int stv[NS];
#pragma unroll
    for (int s = 0; s < NS; ++s) stv[s] = sb[2 * s];
    auto nxt = [&](int l) {
      int nn = INT_MAX;
#pragma unroll
      for (int s = 0; s < NS; ++s)
        nn = (stv[s] > l && stv[s] < nn) ? stv[s] : nn;
      return nn;
    };
    int ns = nxt(lrow0 - 4);

    const float* gxb = x + (size_t)(b * L_ + lrow0) * C_ + q * 4;

    f32x4 p0[4], p1[4], p2[4], hw[4];
    auto ldg = [&](int g, f32x4 (&p)[4]) {
#pragma unroll
      for (int j = 0; j < 4; ++j)
        p[j] = *(const f32x4*)(gxb + (ptrdiff_t)(g * 4 + j) * C_);
    };
#pragma unroll
    for (int i = 0; i < 4; ++i) {
      const int lw = lrow0 - 4 + i;
      hw[i] = (lw >= 0) ? *(const f32x4*)(gxb + (ptrdiff_t)(i - 4) * C_) : z4;
    }
    ldg(0, p0);
    ldg(1, p1);
    ldg(2, p2);

    f32x4 w0 = z4, w1 = z4, w2 = z4, w3 = z4;
#pragma unroll
    for (int i = 0; i < 4; ++i) {
      const int l = lrow0 - 4 + i;
      if (l == ns) { w0 = z4; w1 = z4; w2 = z4; w3 = z4; ns = nxt(l); }
      w0 = w1; w1 = w2; w2 = w3; w3 = hw[i];
    }

    auto dorow = [&](int l, f32x4& A, f32x4& B4, f32x4& Cc, f32x4& D,
                     const f32x4& E) {
      if (l == ns) { A = z4; B4 = z4; Cc = z4; D = z4; ns = nxt(l); }
      f32x4 r;
#pragma unroll
      for (int i = 0; i < 4; ++i) {
        float a = A[i] * wt[0][i];
        a = fmaf(B4[i], wt[1][i], a);
        a = fmaf(Cc[i], wt[2][i], a);
        a = fmaf(D[i], wt[3][i], a);
        a = fmaf(E[i], wt[4][i], a);
        r[i] = a;
      }
      bf16x4 h;
#pragma unroll
      for (int i = 0; i < 4; ++i) h[i] = (bf16)r[i];
      const int u = q ^ ((l & 7) << 1);  // quad-unit XOR swizzle (per row)
      *(bf16x4*)(dwg + (size_t)(b * L_ + l) * C_ + u * 4) = h;
    };

    auto compute = [&](int g, f32x4 (&p)[4]) {
      const int lb = lrow0 + g * 4;
      dorow(lb + 0, w0, w1, w2, w3, p[0]);
      dorow(lb + 1, w1, w2, w3, p[0], p[1]);
      dorow(lb + 2, w2, w3, p[0], p[1], p[2]);
      dorow(lb + 3, w3, p[0], p[1], p[2], p[3]);
      w0 = p[0]; w1 = p[1]; w2 = p[2]; w3 = p[3];
    };

    // 16 groups, 3-deep rotation (all indices static)
#pragma unroll 1
    for (int g3 = 0; g3 < 12; g3 += 3) {
      compute(g3 + 0, p0); ldg(g3 + 3, p0);
      compute(g3 + 1, p1); ldg(g3 + 4, p1);
      compute(g3 + 2, p2); ldg(g3 + 5, p2);
    }
    compute(12, p0); ldg(15, p0);
    compute(13, p1);
    compute(14, p2);
    compute(15, p0);

    __threadfence();   // make dw visible at agent scope
    __syncthreads();   // all stores in block done
    if (t == 0) {
#pragma unroll
      for (int i = 0; i < 4; ++i)
        __hip_atomic_store(&flags[blk * 4 + i], 1, __ATOMIC_RELEASE,
                           __HIP_MEMORY_SCOPE_AGENT);
    }
  } else {
    // ========================= CONSUMER =========================
    const int cid = blockIdx.x - 128;  // 0..255
    const int wn = t >> 6;             // 0..7
    const int cg = lane >> 4;
    const int rx = lane & 7;

    int aRow[4];
#pragma unroll
    for (int mf = 0; mf < 4; ++mf) aRow[mf] = (mf * 16 + (lane & 15)) * 512;
    const bf16* pw = pk + (size_t)wn * 2048 + lane * 8;

    const int col0 = wn * 64 + (lane & 15);
    float bia[4];
#pragma unroll
    for (int nf = 0; nf < 4; ++nf) bia[nf] = bias2[col0 + nf * 16];

#pragma unroll 1
    for (int half = 0; half < 2; ++half) {
      const int j = cid * 2 + half;  // tile 0..511
      const int b = j >> 6;
      const int l0 = (j & 63) << 6;

      if (t == 0) {
        while (__hip_atomic_load(&flags[j], __ATOMIC_ACQUIRE,
                                 __HIP_MEMORY_SCOPE_AGENT) == 0)
          __builtin_amdgcn_s_sleep(16);
      }
      __syncthreads();
      __threadfence();  // acquire: invalidate stale cache before reading dw

      // 64KB linear DMA (source already swizzled per-row)
      const bf16* asrc = dwg + (size_t)(b * L_ + l0) * C_;
#pragma unroll
      for (int i = 0; i < 8; ++i)
        GLOAD_LDS16(asrc + (i * 512 + t) * 8, As + (i * 512 + (t & ~63)) * 8);
      __syncthreads();  // drains DMA; As ready

      f32x4 acc[4][4];
#pragma unroll
      for (int i = 0; i < 4; ++i)
#pragma unroll
        for (int jj = 0; jj < 4; ++jj) acc[i][jj] = z4;

#pragma unroll 1
      for (int kk = 0; kk < 16; ++kk) {
        const bf16* pws = pw + kk * 16384;
        bf16x8 bb[4];
#pragma unroll
        for (int nf = 0; nf < 4; ++nf)
          bb[nf] = *(const bf16x8*)(pws + nf * 512);
        const int ao = ((kk * 4 + cg) ^ rx) << 3;
        bf16x8 af[4];
#pragma unroll
        for (int mf = 0; mf < 4; ++mf)
          af[mf] = *(const bf16x8*)&As[aRow[mf] + ao];
        __builtin_amdgcn_s_setprio(1);
#pragma unroll
        for (int nf = 0; nf < 4; ++nf)
#pragma unroll
          for (int mf = 0; mf < 4; ++mf)
            acc[mf][nf] = __builtin_amdgcn_mfma_f32_16x16x32_bf16(
                af[mf], bb[nf], acc[mf][nf], 0, 0, 0);
        __builtin_amdgcn_s_setprio(0);
      }

      const int rb0 = l0 + (cg << 2);
#pragma unroll
      for (int mf = 0; mf < 4; ++mf) {
#pragma unroll
        for (int i = 0; i < 4; ++i) {
          const int row = rb0 + mf * 16 + i;
          float* o = out + (size_t)(b * L_ + row) * C_ + col0;
#pragma unroll
          for (int nf = 0; nf < 4; ++nf) o[nf * 16] = acc[mf][nf][i] + bia[nf];
        }
      }
      __syncthreads();  // all waves done with As before next half's DMA
    }
  }
}

extern "C" void kernel_launch(void* const* d_in, const int* in_sizes, int n_in,
                              void* d_out, int out_size, void* d_ws,
                              size_t ws_size, hipStream_t stream) {
  const float* x = (const float*)d_in[0];
  const int* segb = (const int*)d_in[1];      // [B][S][2] int32
  const float* w_dw = (const float*)d_in[2];  // [C][K]
  const float* b_dw = (const float*)d_in[3];  // [C]
  const float* w_pw = (const float*)d_in[4];  // [C_out][C_in]
  const float* b_pw = (const float*)d_in[5];  // [C]
  float* out = (float*)d_out;

  float* bias2 = (float*)d_ws;                        // 4 KB   @ 0
  bf16* pk = (bf16*)((char*)d_ws + 4096);             // 512 KB @ 4K
  int* flags = (int*)((char*)d_ws + 4096 + 524288);   // 2 KB   @ 528K
  bf16* dwg = (bf16*)((char*)d_ws + (1 << 20));       // 32 MB  @ 1M

  hipMemsetAsync(flags, 0, 512 * sizeof(int), stream);
  prep_kernel<<<640, 256, 0, stream>>>(w_pw, b_dw, b_pw, pk, bias2);
  pc_kernel<<<384, 512, 0, stream>>>(x, segb, w_dw, pk, bias2, dwg, flags,
                                     out);
}

// Round 16
// 42.906 us; speedup vs baseline: 6.7613x; 6.7613x over previous
//
#include <hip/hip_runtime.h>
#include <hip/hip_bf16.h>
#include <climits>

typedef __bf16 bf16;
typedef __bf16 bf16x4 __attribute__((ext_vector_type(4)));
typedef __bf16 bf16x8 __attribute__((ext_vector_type(8)));
typedef float f32x4 __attribute__((ext_vector_type(4)));

#define NB 8
#define L_ 4096
#define C_ 512
#define KW 5
#define NS 8
#define BM 64

#define BARRIER_MEM                                                            \
  do {                                                                         \
    __builtin_amdgcn_sched_barrier(0);                                         \
    __builtin_amdgcn_s_barrier();                                              \
    __builtin_amdgcn_sched_barrier(0);                                         \
  } while (0)
#define DSFLUSH_BARRIER                                                        \
  do {                                                                         \
    asm volatile("s_waitcnt lgkmcnt(0)" ::: "memory");                         \
    BARRIER_MEM;                                                               \
  } while (0)

// ---------------------------------------------------------------------------
// prep (merged, unchanged from R14): blocks 0..127 pack w_pw -> bf16 B-frag
// order; blocks 128..639 compute bias2 = b_pw + w_pw . b_dw (fp32-exact).
// pack: gid = ((kk*8 + g)*4 + nf)*64 + lane holds 8 bf16 (16B):
//   col n = g*64 + nf*16 + (lane&15), ch c = kk*32 + (lane>>4)*8 .. +8
// ---------------------------------------------------------------------------
__global__ __launch_bounds__(256) void prep_kernel(
    const float* __restrict__ w_pw, const float* __restrict__ b_dw,
    const float* __restrict__ b_pw, bf16* __restrict__ pk,
    float* __restrict__ bias2) {
  const int t = threadIdx.x;
  if (blockIdx.x < 128) {
    const int gid = blockIdx.x * 256 + t;  // 0..32767
    const int lane = gid & 63;
    const int nf = (gid >> 6) & 3;
    const int g = (gid >> 8) & 7;
    const int kk = gid >> 11;
    const int n = g * 64 + nf * 16 + (lane & 15);
    const int c = kk * 32 + (lane >> 4) * 8;
    const float* s = w_pw + n * C_ + c;
    float4 a = *(const float4*)s;
    float4 b4 = *(const float4*)(s + 4);
    bf16x8 h;
    h[0] = (bf16)a.x; h[1] = (bf16)a.y; h[2] = (bf16)a.z; h[3] = (bf16)a.w;
    h[4] = (bf16)b4.x; h[5] = (bf16)b4.y; h[6] = (bf16)b4.z; h[7] = (bf16)b4.w;
    *(bf16x8*)(pk + (size_t)gid * 8) = h;
  } else {
    const int n = blockIdx.x - 128;  // 0..511
    float2 v = *(const float2*)(w_pw + n * C_ + 2 * t);
    float2 bb = *(const float2*)(b_dw + 2 * t);
    float s = v.x * bb.x + v.y * bb.y;
#pragma unroll
    for (int off = 32; off; off >>= 1) s += __shfl_down(s, off, 64);
    __shared__ float part[4];
    if ((t & 63) == 0) part[t >> 6] = s;
    __syncthreads();
    if (t == 0) bias2[n] = b_pw[n] + part[0] + part[1] + part[2] + part[3];
  }
}

// ---------------------------------------------------------------------------
// fused, wave-role phased (in-block pipeline):
//  P0 (all 8 waves): conv rows 0..31 -> As (8-row strips)        | barrier
//  P1: waves 0-3 GEMM rows 0..31  ||  waves 4-7 conv rows 32..63 | barrier
//  P2: waves 0-3 write rows 0..31 ||  waves 4-7 GEMM+write 32..63
//  => MFMA overlaps x HBM reads (P1); out HBM writes overlap MFMA (P2).
// Grid: 512 blocks x 512 thr; As=64KB -> 2 blocks/CU, 16 waves/CU.
// ---------------------------------------------------------------------------
__global__ __launch_bounds__(512, 2) void fused_kernel(
    const float* __restrict__ x, const int* __restrict__ segb,
    const float* __restrict__ w_dw, const bf16* __restrict__ pk,
    const float* __restrict__ bias2, float* __restrict__ out) {
  __shared__ __align__(16) bf16 As[BM * C_];  // 64 KB

  const int t = threadIdx.x;
  const int lane = t & 63;
  const int wid = t >> 6;
  const int b = blockIdx.x >> 6;          // 64 m-tiles per batch row
  const int l0 = (blockIdx.x & 63) << 6;  // tile * 64

  const f32x4 z4 = (f32x4){0.f, 0.f, 0.f, 0.f};
  const int q = t & 127;  // channel quad (same for both conv phases)

  // ---- conv constants (taps transposed, segment starts)
  float4 raw[5];
#pragma unroll
  for (int i = 0; i < 5; ++i)
    raw[i] = *(const float4*)(w_dw + q * 20 + i * 4);
  f32x4 wt[5];
#pragma unroll
  for (int m = 0; m < 5; ++m)
#pragma unroll
    for (int i = 0; i < 4; ++i) {
      const int f = i * 5 + m;
      wt[m][i] = ((const float*)&raw[f >> 2])[f & 3];
    }
  const int* sb = segb + b * NS * 2;
  int stv[NS];
#pragma unroll
  for (int s = 0; s < NS; ++s) stv[s] = sb[2 * s];
  auto nxt = [&](int l) {
    int nn = INT_MAX;
#pragma unroll
    for (int s = 0; s < NS; ++s)
      nn = (stv[s] > l && stv[s] < nn) ? stv[s] : nn;
    return nn;
  };

  // rolling-window state (shared by both conv phases)
  f32x4 w0 = z4, w1 = z4, w2 = z4, w3 = z4;
  int ns = 0;

  auto dorow = [&](int l, f32x4& A, f32x4& B4, f32x4& Cc, f32x4& D,
                   const f32x4& E, int rloc) {
    if (l == ns) { A = z4; B4 = z4; Cc = z4; D = z4; ns = nxt(l); }
    f32x4 r;
#pragma unroll
    for (int i = 0; i < 4; ++i) {
      float a = A[i] * wt[0][i];
      a = fmaf(B4[i], wt[1][i], a);
      a = fmaf(Cc[i], wt[2][i], a);
      a = fmaf(D[i], wt[3][i], a);
      a = fmaf(E[i], wt[4][i], a);
      r[i] = a;
    }
    bf16x4 h;
#pragma unroll
    for (int i = 0; i < 4; ++i) h[i] = (bf16)r[i];
    const int u = q ^ ((rloc & 7) << 1);  // quad-unit XOR swizzle
    *(bf16x4*)&As[rloc * 512 + u * 4] = h;
  };

  // ================= P0: conv rows 0..31 (all waves, 8-row strips) ========
  {
    const int r0 = (t >> 7) << 3;  // 0/8/16/24
    ns = nxt(l0 + r0 - 4);
    const float* gxb = x + (size_t)(b * L_ + l0 + r0) * C_ + q * 4;
    f32x4 hw[4], p0[4], p1[4];
#pragma unroll
    for (int i = 0; i < 4; ++i) {
      const int lw = l0 + r0 - 4 + i;
      hw[i] = (lw >= 0) ? *(const f32x4*)(gxb + (ptrdiff_t)(i - 4) * C_) : z4;
    }
#pragma unroll
    for (int j = 0; j < 4; ++j)
      p0[j] = *(const f32x4*)(gxb + (ptrdiff_t)j * C_);
#pragma unroll
    for (int j = 0; j < 4; ++j)
      p1[j] = *(const f32x4*)(gxb + (ptrdiff_t)(4 + j) * C_);
#pragma unroll
    for (int i = 0; i < 4; ++i) {
      const int l = l0 + r0 - 4 + i;
      if (l == ns) { w0 = z4; w1 = z4; w2 = z4; w3 = z4; ns = nxt(l); }
      w0 = w1; w1 = w2; w2 = w3; w3 = hw[i];
    }
    const int lb = l0 + r0;
    dorow(lb + 0, w0, w1, w2, w3, p0[0], r0 + 0);
    dorow(lb + 1, w1, w2, w3, p0[0], p0[1], r0 + 1);
    dorow(lb + 2, w2, w3, p0[0], p0[1], p0[2], r0 + 2);
    dorow(lb + 3, w3, p0[0], p0[1], p0[2], p0[3], r0 + 3);
    w0 = p0[0]; w1 = p0[1]; w2 = p0[2]; w3 = p0[3];
    dorow(lb + 4, w0, w1, w2, w3, p1[0], r0 + 4);
    dorow(lb + 5, w1, w2, w3, p1[0], p1[1], r0 + 5);
    dorow(lb + 6, w2, w3, p1[0], p1[1], p1[2], r0 + 6);
    dorow(lb + 7, w3, p1[0], p1[1], p1[2], p1[3], r0 + 7);
  }

  // ---- shared GEMM helper: 1 wave, 32 rows (rowOff..+31) x 128 cols
  const int cg = lane >> 4;
  const int rx = lane & 7;
  f32x4 acc[2][8];
#pragma unroll
  for (int i = 0; i < 2; ++i)
#pragma unroll
    for (int j = 0; j < 8; ++j) acc[i][j] = z4;

  auto gemm_half = [&](int rowOff, int wn) {
    const int aRow0 = (rowOff + (lane & 15)) * 512;
    const int aRow1 = aRow0 + 16 * 512;
    const bf16* pb = pk + (size_t)wn * 4096 + lane * 8;
#pragma unroll 1
    for (int kk = 0; kk < 16; ++kk) {
      const bf16* pws = pb + kk * 16384;
      bf16x8 bb[8];
#pragma unroll
      for (int nf = 0; nf < 8; ++nf)
        bb[nf] = *(const bf16x8*)(pws + nf * 512);
      const int ao = ((kk * 4 + cg) ^ rx) << 3;
      bf16x8 a0 = *(const bf16x8*)&As[aRow0 + ao];
      bf16x8 a1 = *(const bf16x8*)&As[aRow1 + ao];
      __builtin_amdgcn_s_setprio(1);
#pragma unroll
      for (int nf = 0; nf < 8; ++nf) {
        acc[0][nf] = __builtin_amdgcn_mfma_f32_16x16x32_bf16(a0, bb[nf],
                                                             acc[0][nf], 0, 0, 0);
        acc[1][nf] = __builtin_amdgcn_mfma_f32_16x16x32_bf16(a1, bb[nf],
                                                             acc[1][nf], 0, 0, 0);
      }
      __builtin_amdgcn_s_setprio(0);
    }
  };

  auto epilogue = [&](int rowOff, int wn) {
    const int col0 = wn * 128 + (lane & 15);
    float bia[8];
#pragma unroll
    for (int nf = 0; nf < 8; ++nf) bia[nf] = bias2[col0 + nf * 16];
    const int rb0 = l0 + rowOff + (cg << 2);
#pragma unroll
    for (int mf = 0; mf < 2; ++mf) {
#pragma unroll
      for (int i = 0; i < 4; ++i) {
        const int row = rb0 + mf * 16 + i;
        float* o = out + (size_t)(b * L_ + row) * C_ + col0;
#pragma unroll
        for (int nf = 0; nf < 8; ++nf) o[nf * 16] = acc[mf][nf][i] + bia[nf];
      }
    }
  };

  DSFLUSH_BARRIER;  // bar1: rows 0..31 published

  if (wid < 4) {
    // ============ P1: GEMM rows 0..31 ============
    gemm_half(0, wid);
    BARRIER_MEM;  // bar2
    // ============ P2: write rows 0..31 ============
    epilogue(0, wid);
  } else {
    // ============ P1: conv rows 32..63 (16-row strips, 3-deep) ============
    const int r0 = 32 + (((t >> 7) - 2) << 4);  // 32 or 48
    ns = nxt(l0 + r0 - 4);
    const float* gxb = x + (size_t)(b * L_ + l0 + r0) * C_ + q * 4;
    f32x4 p0[4], p1[4], p2[4];
    auto ldg = [&](int g, f32x4 (&p)[4]) {
#pragma unroll
      for (int j = 0; j < 4; ++j)
        p[j] = *(const f32x4*)(gxb + (ptrdiff_t)(g * 4 + j) * C_);
    };
    ldg(0, p0);
    ldg(1, p1);
    ldg(2, p2);
    w0 = z4; w1 = z4; w2 = z4; w3 = z4;
#pragma unroll
    for (int i = 0; i < 4; ++i) {
      const int l = l0 + r0 - 4 + i;  // >= 28, no clamp needed
      f32x4 nv = *(const f32x4*)(gxb + (ptrdiff_t)(i - 4) * C_);
      if (l == ns) { w0 = z4; w1 = z4; w2 = z4; w3 = z4; ns = nxt(l); }
      w0 = w1; w1 = w2; w2 = w3; w3 = nv;
    }
    auto compute = [&](int g, f32x4 (&p)[4]) {
      const int lb = l0 + r0 + g * 4;
      const int rl = r0 + g * 4;
      dorow(lb + 0, w0, w1, w2, w3, p[0], rl + 0);
      dorow(lb + 1, w1, w2, w3, p[0], p[1], rl + 1);
      dorow(lb + 2, w2, w3, p[0], p[1], p[2], rl + 2);
      dorow(lb + 3, w3, p[0], p[1], p[2], p[3], rl + 3);
      w0 = p[0]; w1 = p[1]; w2 = p[2]; w3 = p[3];
    };
    compute(0, p0);
    ldg(3, p0);
    compute(1, p1);
    compute(2, p2);
    compute(3, p0);

    DSFLUSH_BARRIER;  // bar2: rows 32..63 published
    // ============ P2: GEMM + write rows 32..63 ============
    gemm_half(32, wid - 4);
    epilogue(32, wid - 4);
  }
}

extern "C" void kernel_launch(void* const* d_in, const int* in_sizes, int n_in,
                              void* d_out, int out_size, void* d_ws,
                              size_t ws_size, hipStream_t stream) {
  const float* x = (const float*)d_in[0];
  const int* segb = (const int*)d_in[1];      // [B][S][2] int32
  const float* w_dw = (const float*)d_in[2];  // [C][K]
  const float* b_dw = (const float*)d_in[3];  // [C]
  const float* w_pw = (const float*)d_in[4];  // [C_out][C_in]
  const float* b_pw = (const float*)d_in[5];  // [C]
  float* out = (float*)d_out;

  float* bias2 = (float*)d_ws;             // 4 KB
  bf16* pk = (bf16*)((char*)d_ws + 4096);  // 512 KB packed B

  prep_kernel<<<640, 256, 0, stream>>>(w_pw, b_dw, b_pw, pk, bias2);
  fused_kernel<<<NB * L_ / BM, 512, 0, stream>>>(x, segb, w_dw, pk, bias2,
                                                 out);
}

// Round 17
// 39.985 us; speedup vs baseline: 7.2553x; 1.0731x over previous
//
#include <hip/hip_runtime.h>
#include <hip/hip_bf16.h>
#include <climits>

typedef __bf16 bf16;
typedef __bf16 bf16x4 __attribute__((ext_vector_type(4)));
typedef __bf16 bf16x8 __attribute__((ext_vector_type(8)));
typedef float f32x4 __attribute__((ext_vector_type(4)));

#define NB 8
#define L_ 4096
#define C_ 512
#define KW 5
#define NS 8
#define BM 64

// ---------------------------------------------------------------------------
// prep (merged): blocks 0..127 pack w_pw -> bf16 MFMA B-frag order;
//                blocks 128..639 compute bias2[n] = b_pw[n] + w_pw[n,:].b_dw
// ---------------------------------------------------------------------------
__global__ __launch_bounds__(256) void prep_kernel(
    const float* __restrict__ w_pw, const float* __restrict__ b_dw,
    const float* __restrict__ b_pw, bf16* __restrict__ pk,
    float* __restrict__ bias2) {
  const int t = threadIdx.x;
  if (blockIdx.x < 128) {
    const int gid = blockIdx.x * 256 + t;  // 0..32767
    const int lane = gid & 63;
    const int nf = (gid >> 6) & 3;
    const int wnn = (gid >> 8) & 7;
    const int kk = gid >> 11;
    const int n = wnn * 64 + nf * 16 + (lane & 15);
    const int c = kk * 32 + (lane >> 4) * 8;
    const float* s = w_pw + n * C_ + c;
    float4 a = *(const float4*)s;
    float4 b4 = *(const float4*)(s + 4);
    bf16x8 h;
    h[0] = (bf16)a.x; h[1] = (bf16)a.y; h[2] = (bf16)a.z; h[3] = (bf16)a.w;
    h[4] = (bf16)b4.x; h[5] = (bf16)b4.y; h[6] = (bf16)b4.z; h[7] = (bf16)b4.w;
    *(bf16x8*)(pk + (size_t)gid * 8) = h;
  } else {
    const int n = blockIdx.x - 128;  // 0..511
    float2 v = *(const float2*)(w_pw + n * C_ + 2 * t);
    float2 bb = *(const float2*)(b_dw + 2 * t);
    float s = v.x * bb.x + v.y * bb.y;
#pragma unroll
    for (int off = 32; off; off >>= 1) s += __shfl_down(s, off, 64);
    __shared__ float part[4];
    if ((t & 63) == 0) part[t >> 6] = s;
    __syncthreads();
    if (t == 0) bias2[n] = b_pw[n] + part[0] + part[1] + part[2] + part[3];
  }
}

// ---------------------------------------------------------------------------
// fused (R14 structure, 39.9 µs) + slot stagger:
//  blocks 256..511 (second residency slot per CU) sleep ~4.5 µs first, so
//  slot-B conv (HBM read) overlaps slot-A GEMM (L2/MFMA), and slot-B GEMM
//  overlaps slot-A epilogue writes (HBM-W) -> chip-wide phase mixing.
//  Phase A: register rolling-window segment-causal conv, 64 rows x 512 ch
//           -> LDS A-tile (bf16, chunk-XOR swizzle), 3-deep prefetch.
//  ONE __syncthreads().
//  Phase B: barrier-free GEMM, 1Mx8N: 8 waves x (64 rows x 64 cols),
//           acc[4][4]; B-frags from packed pk, L2->VGPR, 16B/lane.
// Grid: 512 blocks x 512 thr; As=64KB -> 2 blocks/CU, 16 waves/CU.
// ---------------------------------------------------------------------------
__global__ __launch_bounds__(512, 4) void fused_kernel(
    const float* __restrict__ x, const int* __restrict__ segb,
    const float* __restrict__ w_dw, const bf16* __restrict__ pk,
    const float* __restrict__ bias2, float* __restrict__ out) {
  __shared__ __align__(16) bf16 As[BM * C_];  // 64 KB

  const int t = threadIdx.x;
  const int lane = t & 63;
  const int b = blockIdx.x >> 6;          // 64 m-tiles per batch row
  const int l0 = (blockIdx.x & 63) << 6;  // tile * 64

  // ---- slot stagger: second residency slot sleeps ~4.5 us (wave-uniform)
  if (blockIdx.x & 256) {
#pragma unroll 1
    for (int i = 0; i < 24; ++i) __builtin_amdgcn_s_sleep(7);
  }

  // ================= Phase A: conv -> As =================
  const int q = t & 127;         // channel quad (4 ch)
  const int r0 = (t >> 7) << 4;  // row strip 0/16/32/48

  float4 raw[5];
#pragma unroll
  for (int i = 0; i < 5; ++i)
    raw[i] = *(const float4*)(w_dw + q * 20 + i * 4);
  f32x4 wt[5];
#pragma unroll
  for (int m = 0; m < 5; ++m)
#pragma unroll
    for (int i = 0; i < 4; ++i) {
      const int f = i * 5 + m;
      wt[m][i] = ((const float*)&raw[f >> 2])[f & 3];
    }

  const int* sb = segb + b * NS * 2;
  int stv[NS];
#pragma unroll
  for (int s = 0; s < NS; ++s) stv[s] = sb[2 * s];
  auto nxt = [&](int l) {
    int nn = INT_MAX;
#pragma unroll
    for (int s = 0; s < NS; ++s)
      nn = (stv[s] > l && stv[s] < nn) ? stv[s] : nn;
    return nn;
  };
  int ns = nxt(l0 + r0 - 4);

  const float* gxb = x + (size_t)(b * L_ + l0 + r0) * C_ + q * 4;

  const f32x4 z4 = (f32x4){0.f, 0.f, 0.f, 0.f};
  f32x4 w0 = z4, w1 = z4, w2 = z4, w3 = z4;

  // 3-deep row-group prefetch buffers
  f32x4 p0[4], p1[4], p2[4];
  auto ldg = [&](int g, f32x4 (&p)[4]) {
#pragma unroll
    for (int j = 0; j < 4; ++j)
      p[j] = *(const f32x4*)(gxb + (ptrdiff_t)(g * 4 + j) * C_);
  };
  ldg(0, p0);
  ldg(1, p1);
  ldg(2, p2);

  // warmup rows l0+r0-4 .. l0+r0-1 (zero left edge / segment resets)
#pragma unroll
  for (int i = 0; i < 4; ++i) {
    const int l = l0 + r0 - 4 + i;
    f32x4 nv = z4;
    if (l >= 0) nv = *(const f32x4*)(gxb + (ptrdiff_t)(i - 4) * C_);
    if (l == ns) { w0 = z4; w1 = z4; w2 = z4; w3 = z4; ns = nxt(l); }
    w0 = w1; w1 = w2; w2 = w3; w3 = nv;
  }

  auto dorow = [&](int l, f32x4& A, f32x4& B4, f32x4& Cc, f32x4& D,
                   const f32x4& E, int rloc) {
    if (l == ns) { A = z4; B4 = z4; Cc = z4; D = z4; ns = nxt(l); }
    f32x4 r;
#pragma unroll
    for (int i = 0; i < 4; ++i) {
      float a = A[i] * wt[0][i];
      a = fmaf(B4[i], wt[1][i], a);
      a = fmaf(Cc[i], wt[2][i], a);
      a = fmaf(D[i], wt[3][i], a);
      a = fmaf(E[i], wt[4][i], a);
      r[i] = a;
    }
    bf16x4 h;
#pragma unroll
    for (int i = 0; i < 4; ++i) h[i] = (bf16)r[i];
    const int u = q ^ ((rloc & 7) << 1);  // quad-unit XOR swizzle
    *(bf16x4*)&As[rloc * 512 + u * 4] = h;
  };

  auto compute = [&](int g, f32x4 (&p)[4]) {
    const int lb = l0 + r0 + g * 4;
    dorow(lb + 0, w0, w1, w2, w3, p[0], r0 + g * 4 + 0);
    dorow(lb + 1, w1, w2, w3, p[0], p[1], r0 + g * 4 + 1);
    dorow(lb + 2, w2, w3, p[0], p[1], p[2], r0 + g * 4 + 2);
    dorow(lb + 3, w3, p[0], p[1], p[2], p[3], r0 + g * 4 + 3);
    w0 = p[0]; w1 = p[1]; w2 = p[2]; w3 = p[3];
  };

  compute(0, p0);
  ldg(3, p0);  // reuse p0 for the last group
  compute(1, p1);
  compute(2, p2);
  compute(3, p0);

  __syncthreads();  // the ONLY barrier: As now read-only

  // ================= Phase B: barrier-free GEMM (1M x 8N) =================
  const int wn = t >> 6;     // 0..7
  const int cg = lane >> 4;  // k-chunk group
  const int rx = lane & 7;

  int aRow[4];
#pragma unroll
  for (int mf = 0; mf < 4; ++mf) aRow[mf] = (mf * 16 + (lane & 15)) * 512;
  const bf16* pw = pk + (size_t)wn * 2048 + lane * 8;  // packed-B wave base

  f32x4 acc[4][4];
#pragma unroll
  for (int i = 0; i < 4; ++i)
#pragma unroll
    for (int j = 0; j < 4; ++j) acc[i][j] = z4;

#pragma unroll 1
  for (int kk = 0; kk < 16; ++kk) {
    const bf16* pws = pw + kk * 16384;
    bf16x8 bb[4];
#pragma unroll
    for (int nf = 0; nf < 4; ++nf)
      bb[nf] = *(const bf16x8*)(pws + nf * 512);
    const int ao = ((kk * 4 + cg) ^ rx) << 3;
    bf16x8 af[4];
#pragma unroll
    for (int mf = 0; mf < 4; ++mf)
      af[mf] = *(const bf16x8*)&As[aRow[mf] + ao];
    __builtin_amdgcn_s_setprio(1);
#pragma unroll
    for (int nf = 0; nf < 4; ++nf)
#pragma unroll
      for (int mf = 0; mf < 4; ++mf)
        acc[mf][nf] = __builtin_amdgcn_mfma_f32_16x16x32_bf16(
            af[mf], bb[nf], acc[mf][nf], 0, 0, 0);
    __builtin_amdgcn_s_setprio(0);
  }

  // ---- epilogue: fp32 + bias2 (b_pw + W.b_dw folded, fp32-exact)
  const int col0 = wn * 64 + (lane & 15);
  float bia[4];
#pragma unroll
  for (int nf = 0; nf < 4; ++nf) bia[nf] = bias2[col0 + nf * 16];
  const int rb0 = l0 + (cg << 2);
#pragma unroll
  for (int mf = 0; mf < 4; ++mf) {
#pragma unroll
    for (int i = 0; i < 4; ++i) {
      const int row = rb0 + mf * 16 + i;
      float* o = out + (size_t)(b * L_ + row) * C_ + col0;
#pragma unroll
      for (int nf = 0; nf < 4; ++nf) o[nf * 16] = acc[mf][nf][i] + bia[nf];
    }
  }
}

extern "C" void kernel_launch(void* const* d_in, const int* in_sizes, int n_in,
                              void* d_out, int out_size, void* d_ws,
                              size_t ws_size, hipStream_t stream) {
  const float* x = (const float*)d_in[0];
  const int* segb = (const int*)d_in[1];      // [B][S][2] int32
  const float* w_dw = (const float*)d_in[2];  // [C][K]
  const float* b_dw = (const float*)d_in[3];  // [C]
  const float* w_pw = (const float*)d_in[4];  // [C_out][C_in]
  const float* b_pw = (const float*)d_in[5];  // [C]
  float* out = (float*)d_out;

  float* bias2 = (float*)d_ws;             // 4 KB
  bf16* pk = (bf16*)((char*)d_ws + 4096);  // 512 KB packed B

  prep_kernel<<<640, 256, 0, stream>>>(w_pw, b_dw, b_pw, pk, bias2);
  fused_kernel<<<NB * L_ / BM, 512, 0, stream>>>(x, segb, w_dw, pk, bias2,
                                                 out);
}